// Round 11
// baseline (2376.834 us; speedup 1.0000x reference)
//
#include <hip/hip_runtime.h>

#define BB 64
#define SS 2048
#define II 128
#define HH 256
#define OO 128
#define GG 16          // batches per scan block (= MFMA N)
#define RS 264         // f16 row stride per batch-col in LDS (16B aligned)

typedef _Float16 half8 __attribute__((ext_vector_type(8)));
typedef float    f32x4 __attribute__((ext_vector_type(4)));
typedef _Float16 h2_t  __attribute__((ext_vector_type(2)));

#define SC2LOG2E 2.8853900817779268f   // 2*log2(e): exp2(SC*s) = e^{2s}

// ---------------------------------------------------------------------------
// Prep: transpose W_ih -> [I][H] (scaled), W_fc -> [H][O], combined bias
// (scaled), W_hh -> f16 pairs (scaled). Scaling by 2*log2(e) folds the
// tanh exponent prep into the GEMM/MFMA so tanh needs no multiply.
// hidden stored by the scan is UNSCALED tanh, so wfcT/b_fc stay unscaled.
// ---------------------------------------------------------------------------
__global__ void prep_kernel(const float* __restrict__ W_ih, const float* __restrict__ b_ih,
                            const float* __restrict__ b_hh, const float* __restrict__ W_fc,
                            float* __restrict__ wihT, float* __restrict__ wfcT,
                            float* __restrict__ biasc, unsigned* __restrict__ whh16,
                            const float* __restrict__ W_hh) {
    int idx = blockIdx.x * 256 + threadIdx.x;
    if (idx < HH * II) {            // W_ih [H][I] -> wihT [I][H], scaled
        int j = idx / II, k = idx % II;
        wihT[k * HH + j] = W_ih[idx] * SC2LOG2E;
    }
    if (idx < OO * HH) {            // W_fc [O][H] -> wfcT [H][O], unscaled
        int j = idx / HH, k = idx % HH;
        wfcT[k * OO + j] = W_fc[idx];
    }
    if (idx < HH * (HH / 2)) {      // W_hh -> packed f16 pairs, scaled
        int j = idx / (HH / 2), i = idx % (HH / 2);
        union { h2_t h; unsigned u; } pk;
        pk.h.x = (_Float16)(W_hh[j * HH + 2 * i]     * SC2LOG2E);
        pk.h.y = (_Float16)(W_hh[j * HH + 2 * i + 1] * SC2LOG2E);
        whh16[idx] = pk.u;
    }
    if (idx < HH) biasc[idx] = (b_ih[idx] + b_hh[idx]) * SC2LOG2E;
}

// ---------------------------------------------------------------------------
// Generic row-major GEMM: C[r][j] = sum_k A[r][k] * Wt[k][j] + bias[j]
// 256 threads, 8x8 micro-tile per thread. (unchanged — scan dominates)
// ---------------------------------------------------------------------------
template<int KD, int JD, int RT>
__global__ __launch_bounds__(256, 2)
void gemm_rk(const float* __restrict__ A, const float* __restrict__ Wt,
             const float* __restrict__ bias, float* __restrict__ C) {
    constexpr int KT = 64;
    constexpr int TJ = JD / 8;
    constexpr int TR = RT / 8;
    static_assert(TJ * TR == 256, "bad tiling");

    __shared__ __align__(16) float a_lds[RT][KT];
    __shared__ __align__(16) float w_lds[KT][JD];

    const int tid = threadIdx.x;
    const int tj = tid % TJ;
    const int tr = tid / TJ;
    const long r0 = (long)blockIdx.x * RT;

    float acc[8][8];
#pragma unroll
    for (int r = 0; r < 8; ++r)
#pragma unroll
        for (int j = 0; j < 8; ++j) acc[r][j] = 0.0f;

    for (int kt = 0; kt < KD; kt += KT) {
        {
            constexpr int NF4 = RT * KT / 4;
#pragma unroll
            for (int f = 0; f < NF4 / 256; ++f) {
                int fl = f * 256 + tid;
                int rr = fl / (KT / 4), kk4 = fl % (KT / 4);
                *(float4*)&a_lds[rr][kk4 * 4] =
                    *(const float4*)&A[(r0 + rr) * KD + kt + kk4 * 4];
            }
        }
        {
            constexpr int NF4 = KT * JD / 4;
#pragma unroll
            for (int f = 0; f < NF4 / 256; ++f) {
                int fl = f * 256 + tid;
                int kk = fl / (JD / 4), jj4 = fl % (JD / 4);
                *(float4*)&w_lds[kk][jj4 * 4] =
                    *(const float4*)&Wt[(long)(kt + kk) * JD + jj4 * 4];
            }
        }
        __syncthreads();

#pragma unroll 4
        for (int k4 = 0; k4 < KT; k4 += 4) {
            float4 xv[8];
#pragma unroll
            for (int r = 0; r < 8; ++r)
                xv[r] = *(const float4*)&a_lds[tr * 8 + r][k4];
#pragma unroll
            for (int i = 0; i < 4; ++i) {
                float4 wa = *(const float4*)&w_lds[k4 + i][tj * 8];
                float4 wb = *(const float4*)&w_lds[k4 + i][tj * 8 + 4];
#pragma unroll
                for (int r = 0; r < 8; ++r) {
                    float xs = (i == 0) ? xv[r].x : (i == 1) ? xv[r].y
                             : (i == 2) ? xv[r].z : xv[r].w;
                    acc[r][0] = fmaf(xs, wa.x, acc[r][0]);
                    acc[r][1] = fmaf(xs, wa.y, acc[r][1]);
                    acc[r][2] = fmaf(xs, wa.z, acc[r][2]);
                    acc[r][3] = fmaf(xs, wa.w, acc[r][3]);
                    acc[r][4] = fmaf(xs, wb.x, acc[r][4]);
                    acc[r][5] = fmaf(xs, wb.y, acc[r][5]);
                    acc[r][6] = fmaf(xs, wb.z, acc[r][6]);
                    acc[r][7] = fmaf(xs, wb.w, acc[r][7]);
                }
            }
        }
        __syncthreads();
    }

    float4 b0 = *(const float4*)&bias[tj * 8];
    float4 b1 = *(const float4*)&bias[tj * 8 + 4];
#pragma unroll
    for (int r = 0; r < 8; ++r) {
        long row = r0 + tr * 8 + r;
        float4 o0, o1;
        o0.x = acc[r][0] + b0.x; o0.y = acc[r][1] + b0.y;
        o0.z = acc[r][2] + b0.z; o0.w = acc[r][3] + b0.w;
        o1.x = acc[r][4] + b1.x; o1.y = acc[r][5] + b1.y;
        o1.z = acc[r][6] + b1.z; o1.w = acc[r][7] + b1.w;
        *(float4*)&C[row * JD + tj * 8]     = o0;
        *(float4*)&C[row * JD + tj * 8 + 4] = o1;
    }
}

// tanh from pre-scaled input: sc = 2*log2e*s  ->  tanh(s) = 1 - 2/(exp2(sc)+1)
__device__ __forceinline__ float tanh_scaled(float sc) {
    float e = exp2f(sc);                     // v_exp_f32 (native exp2)
    return 1.0f - __fdividef(2.0f, e + 1.0f);
}

// ---------------------------------------------------------------------------
// Sequential scan v7 (MFMA, 4 waves): H_t[256x16] = tanh(XP_t + W_hh H_{t-1})
// in-place over (scaled) xproj. 4 blocks x 256 threads (4 waves, 1/SIMD).
//
// v6 lesson (counters): 8 waves all read the IDENTICAL 8KB H from LDS ->
// 64 ds_read_b128/step (~770 cyc) + 320 conflict-cyc dominated the step
// (2294 cyc) while per-wave compute was only ~300-400 cyc: latency-bound
// with a saturated LDS pipe. v7 halves the waves -> halves LDS instructions;
// each wave owns 64 rows = 4 row-tiles -> 32 MFMA as 4 independent chains
// (ILP replaces TLP). waves_per_eu(1,1) -> 512-reg budget, no demotion
// pressure; a_f in AGPRs is free (MFMA reads AGPRs natively).
//
// Per thread/step: 8 ds_read_b128 (B frags, shared by all 4 tiles),
// 32 mfma_16x16x32_f16, 16 adds, 16 tanh (exp2+rcp), 8 f16 cvt,
// 4 ds_write_b64, 4 f32x4 global stores, 4 f32x4 xp prefetch loads.
// ONE barrier per step, double-buffered H.
// ---------------------------------------------------------------------------
__global__ __attribute__((amdgpu_waves_per_eu(1, 1))) __launch_bounds__(256)
void rnn_scan(const unsigned* __restrict__ whh16, float* __restrict__ hid) {
    const int bg  = blockIdx.x;          // batch group (16 batches)
    const int tid = threadIdx.x;
    const int w   = tid >> 6;            // wave 0..3
    const int l   = tid & 63;
    const int c   = l & 15;              // batch col / A-row within tile
    const int q   = l >> 4;              // k-subgroup / D-row group

    __shared__ __align__(16) _Float16 h16[2][GG][RS];

    // A fragments (scaled f16 weights): 4 row-tiles x 8 k-tiles
    half8 a_f[4][8];
#pragma unroll
    for (int rt = 0; rt < 4; ++rt) {
        const unsigned* wp = &whh16[(size_t)(w * 64 + rt * 16 + c) * (HH / 2)];
#pragma unroll
        for (int kt = 0; kt < 8; ++kt)
            a_f[rt][kt] = *(const half8*)&wp[kt * 16 + q * 4];
    }

    // zero both H buffers (h_{-1} = 0)
    for (int i = tid; i < 2 * GG * RS / 2; i += 256) ((unsigned*)h16)[i] = 0u;

    float* __restrict__ basec = hid + (size_t)(bg * GG + c) * SS * HH;
    const int r0 = w * 64 + q * 4;       // D rows for tile rt: r0 + rt*16

    // xp prefetch pipeline, depth 2 (xp is SCALED by 2log2e from the GEMM)
    f32x4 xp0[4], xp1[4];
#pragma unroll
    for (int rt = 0; rt < 4; ++rt) {
        xp0[rt] = *(const f32x4*)(basec + r0 + rt * 16);
        xp1[rt] = *(const f32x4*)(basec + HH + r0 + rt * 16);
    }
    __syncthreads();

    int cur = 0;
#pragma unroll 1
    for (int t = 0; t < SS; ++t) {
        // branch-free clamped prefetch for t+2 (reads precede overwrite at t)
        const int t2 = (t + 2 < SS) ? (t + 2) : (SS - 1);
        f32x4 xp2[4];
#pragma unroll
        for (int rt = 0; rt < 4; ++rt)
            xp2[rt] = *(const f32x4*)(basec + (size_t)t2 * HH + r0 + rt * 16);

        // B fragments: 8 x b128, shared across all 4 row-tile chains
        half8 bf[8];
#pragma unroll
        for (int kt = 0; kt < 8; ++kt)
            bf[kt] = *(const half8*)&h16[cur][c][kt * 32 + q * 8];

        f32x4 acc[4];
#pragma unroll
        for (int rt = 0; rt < 4; ++rt) acc[rt] = (f32x4){0.f, 0.f, 0.f, 0.f};
#pragma unroll
        for (int kt = 0; kt < 8; ++kt) {
            acc[0] = __builtin_amdgcn_mfma_f32_16x16x32_f16(a_f[0][kt], bf[kt], acc[0], 0, 0, 0);
            acc[1] = __builtin_amdgcn_mfma_f32_16x16x32_f16(a_f[1][kt], bf[kt], acc[1], 0, 0, 0);
            acc[2] = __builtin_amdgcn_mfma_f32_16x16x32_f16(a_f[2][kt], bf[kt], acc[2], 0, 0, 0);
            acc[3] = __builtin_amdgcn_mfma_f32_16x16x32_f16(a_f[3][kt], bf[kt], acc[3], 0, 0, 0);
        }

#pragma unroll
        for (int rt = 0; rt < 4; ++rt) {
            f32x4 s = acc[rt] + xp0[rt];
            f32x4 h;
            h.x = tanh_scaled(s.x);
            h.y = tanh_scaled(s.y);
            h.z = tanh_scaled(s.z);
            h.w = tanh_scaled(s.w);

            // fp32 hidden (in-place over xproj)
            *(f32x4*)(basec + (size_t)t * HH + r0 + rt * 16) = h;

            // f16 repack into next H buffer (4 consecutive rows = 8B)
            union { _Float16 hf[4]; uint2 v; } p;
            p.hf[0] = (_Float16)h.x; p.hf[1] = (_Float16)h.y;
            p.hf[2] = (_Float16)h.z; p.hf[3] = (_Float16)h.w;
            *(uint2*)&h16[cur ^ 1][c][r0 + rt * 16] = p.v;

            xp0[rt] = xp1[rt];
            xp1[rt] = xp2[rt];
        }

        __syncthreads();
        cur ^= 1;
    }
}

// ---------------------------------------------------------------------------
extern "C" void kernel_launch(void* const* d_in, const int* in_sizes, int n_in,
                              void* d_out, int out_size, void* d_ws, size_t ws_size,
                              hipStream_t stream) {
    const float* x    = (const float*)d_in[0];
    const float* W_ih = (const float*)d_in[1];
    const float* W_hh = (const float*)d_in[2];
    const float* b_ih = (const float*)d_in[3];
    const float* b_hh = (const float*)d_in[4];
    const float* W_fc = (const float*)d_in[5];
    const float* b_fc = (const float*)d_in[6];

    float* out_fc  = (float*)d_out;                          // [B][S][O]
    float* hidden  = (float*)d_out + (size_t)BB * SS * OO;   // [B][S][H]

    float*    wihT  = (float*)d_ws;                  // [I][H]  32768 f (scaled)
    float*    wfcT  = wihT + II * HH;                // [H][O]  32768 f
    float*    biasc = wfcT + HH * OO;                // [H]       256 f (scaled)
    unsigned* whh16 = (unsigned*)(biasc + HH);       // [H][H/2] 32768 u32 (scaled)

    const long NR = (long)BB * SS;                   // 131072 rows

    prep_kernel<<<128, 256, 0, stream>>>(W_ih, b_ih, b_hh, W_fc,
                                         wihT, wfcT, biasc, whh16, W_hh);
    gemm_rk<II, HH, 64><<<NR / 64, 256, 0, stream>>>(x, wihT, biasc, hidden);
    rnn_scan<<<BB / GG, 256, 0, stream>>>(whh16, hidden);
    gemm_rk<HH, OO, 128><<<NR / 128, 256, 0, stream>>>(hidden, wfcT, b_fc, out_fc);
}